// Round 1
// 640.824 us; speedup vs baseline: 1.3734x; 1.3734x over previous
//
#include <hip/hip_runtime.h>

#define BATCH 2048
#define CIN   512
#define COUT  512
#define GSZ   24
#define NORB  24
#define M_DIM (BATCH*GSZ)   // 49152
#define K_DIM (GSZ*CIN)     // 12288
#define N_DIM COUT          // 512
#define BM 192              // = 8 whole batches (192 = 8*24) -> batch-aligned tiles
#define BN 128
#define BK 64

typedef __bf16 bf16x8 __attribute__((ext_vector_type(8)));
typedef float  f32x4  __attribute__((ext_vector_type(4)));
typedef unsigned short u16;

__device__ __forceinline__ u16 f2bf(float f) {
  union { float f; unsigned u; } v; v.f = f;
  unsigned u = v.u;
  return (u16)((u + 0x7fffu + ((u >> 16) & 1u)) >> 16);  // RNE
}

// ---- pre-pass 1: x fp32 -> bf16 (coalesced both ways) ----
__global__ void convert_x(const float* __restrict__ x, u16* __restrict__ xb, int n4) {
  int t = blockIdx.x * blockDim.x + threadIdx.x;
  if (t >= n4) return;
  const float4 v = *(const float4*)(x + (size_t)t * 4);
  ushort4 o;
  o.x = f2bf(v.x); o.y = f2bf(v.y); o.z = f2bf(v.z); o.w = f2bf(v.w);
  *(ushort4*)(xb + (size_t)t * 4) = o;
}

// ---- pre-pass 2: weight (O,C,R) fp32 -> Bt[o][r*512+c] bf16 ----
#define TROW 520
__global__ void build_bt(const float* __restrict__ w, u16* __restrict__ bt) {
  __shared__ __align__(16) u16 lds[NORB * TROW];
  const int o = blockIdx.x;
  const int t = threadIdx.x;
  const float* wo = w + (size_t)o * K_DIM;
#pragma unroll
  for (int it = 0; it < 12; ++it) {
    const int idx = it * 256 + t;
    const float4 v = *(const float4*)(wo + idx * 4);
    const int k0 = idx * 4;
#pragma unroll
    for (int e = 0; e < 4; ++e) {
      const int k = k0 + e;
      const int c = k / 24;
      const int r = k - c * 24;
      lds[r * TROW + c] = f2bf(e == 0 ? v.x : e == 1 ? v.y : e == 2 ? v.z : v.w);
    }
  }
  __syncthreads();
  u16* bo = bt + (size_t)o * K_DIM;
#pragma unroll
  for (int it = 0; it < 6; ++it) {
    const int eidx = it * 256 + t;
    const int base = eidx * 8;
    const int r = base >> 9;
    const int c0 = base & 511;
    const uint4 v = *(const uint4*)(lds + r * TROW + c0);
    *(uint4*)(bo + base) = v;
  }
}

// ---- main GEMM: C[M,512] = A[M,K] * B[K,512] + bias ----
// Group-structure A-reuse: for fixed orbit r, i -> jmap[i][r] is a BIJECTION on
// 0..23 (free pair-orbit action). With batch-aligned BM=192 (8 whole batches),
// the A tile at every r is a row-permutation of the same xb slab. So:
//   - outer loop kb (8 c-chunks of 64): stage A slab (192 rows x 64) ONCE
//   - inner loop r (24 orbits): stage only B(r,kb) (128 x 64), double-buffered,
//     prefetched 2 iterations ahead so the barrier's vmcnt(0) drain is ~free.
//   - A rows permuted AT READ TIME via jmap (chunk-XOR swizzle keyed on the
//     permuted row, so swizzle stays consistent with linear staging).
// Cuts A global traffic 24x (FETCH 2.4 GB -> ~0.3 GB) and halves per-barrier
// load count; 48-MFMA cluster per iter; 2 blocks/CU (58.7 KB LDS) for overlap.
__launch_bounds__(256, 2)
__global__ void gemm_gc(const u16* __restrict__ xb, const u16* __restrict__ bt,
                        const float* __restrict__ bias, const int* __restrict__ pair_orbit,
                        float* __restrict__ out) {
  __shared__ __align__(16) u16 As[BM * BK];        // 24 KB, single buffer (per kb)
  __shared__ __align__(16) u16 Bs[2 * BN * BK];    // 32 KB, double buffer (per r)
  __shared__ int jmap[GSZ * 25];                   // stride 25: conflict-free reads

  const int t   = threadIdx.x;
  const int gid = blockIdx.x;
  // XCD-aware: each XCD owns one 128-col B slice (3 MB -> L2-resident).
  const int xcd = gid & 7;
  const int n0  = (xcd & 3) * BN;
  const int m0  = ((gid >> 3) * 2 + (xcd >> 2)) * BM;

  // invert pair_orbit -> jmap[i][r] = j   (jmap[i*25 + r])
  for (int idx = t; idx < GSZ * NORB; idx += 256) {
    const int i = idx / 24;
    const int j = idx - i * 24;
    jmap[i * 25 + pair_orbit[idx]] = j;
  }

  // staging constants: thread t owns 16B chunk (it*256+t); row = it*32 + (t>>3),
  // stored slot = t&7, so source chunk = (t&7) ^ ((t>>3)&7)  (const per thread).
  const int tr0 = t >> 3;
  const int kcg = ((t & 7) ^ (tr0 & 7)) * 8;       // pre-swizzled source chunk (elems)
  const u16* aSrc = xb + (size_t)(m0 + tr0) * CIN + kcg;   // slab rows ARE xb rows m0..m0+191
  const u16* bSrc = bt + (size_t)(n0 + tr0) * K_DIM + kcg;
  u16* aDst = (u16*)As + t * 8;
  u16* bDst = (u16*)Bs + t * 8;

  auto stage_a = [&](int kb) {
#pragma unroll
    for (int it = 0; it < 6; ++it)
      __builtin_amdgcn_global_load_lds(
          (__attribute__((address_space(1))) void*)(aSrc + (size_t)it * 32 * CIN + kb * 64),
          (__attribute__((address_space(3))) void*)(aDst + it * 2048), 16, 0, 0);
  };
  auto stage_b = [&](int kb, int r, int soffElems) {
#pragma unroll
    for (int it = 0; it < 4; ++it)
      __builtin_amdgcn_global_load_lds(
          (__attribute__((address_space(1))) void*)(bSrc + (size_t)it * 32 * K_DIM + r * 512 + kb * 64),
          (__attribute__((address_space(3))) void*)(bDst + soffElems + it * 2048), 16, 0, 0);
  };

  // 4 waves, 2M x 2N, per-wave 96x64 output (6 x 4 fragments)
  const int w    = t >> 6;
  const int lane = t & 63;
  const int lm   = lane & 15;
  const int q    = lane >> 4;
  const int mw   = (w >> 1) * 96;
  const int nw   = (w & 1) * 64;
  const int q8   = q << 3;

  int b24[6], i25[6];
#pragma unroll
  for (int f = 0; f < 6; ++f) {
    const int tr = mw + f * 16 + lm;   // tile row this lane reads for frag f
    const int b  = tr / 24;
    b24[f] = b * 24;
    i25[f] = (tr - b * 24) * 25;
  }
  int baseB[4];
#pragma unroll
  for (int nf = 0; nf < 4; ++nf)
    baseB[nf] = (nw + lm + 16 * nf) * 64 + (q8 ^ ((lm & 7) << 3));

  f32x4 acc[6][4];
#pragma unroll
  for (int i = 0; i < 6; ++i)
#pragma unroll
    for (int j = 0; j < 4; ++j)
      acc[i][j] = (f32x4){0.f, 0.f, 0.f, 0.f};

  stage_a(0);
  stage_b(0, 0, 0);
  __syncthreads();                 // jmap + A(kb=0) + B(0,0) ready
  stage_b(0, 1, 8192);             // B(t=1) in flight during first compute

  int rowC[6];                     // permuted A rows for current r
#pragma unroll
  for (int f = 0; f < 6; ++f) rowC[f] = b24[f] + jmap[i25[f]];   // r = 0

  for (int kb = 0; kb < 8; ++kb) {
    for (int r = 0; r < 24; ++r) {
      const int soff = (r & 1) * 8192;     // current B buffer (elems)

      // A addresses: swizzle keyed on the PERMUTED row (b24%8==0 -> row&7 == j&7)
      int c0[6];
#pragma unroll
      for (int f = 0; f < 6; ++f)
        c0[f] = rowC[f] * 64 + (q8 ^ ((rowC[f] & 7) << 3));

      // prefetch next-r permuted rows (hides jmap ds_read under the MFMA cluster)
      int rowN[6];
      const int rn = (r == 23) ? 0 : (r + 1);
#pragma unroll
      for (int f = 0; f < 6; ++f) rowN[f] = b24[f] + jmap[i25[f] + rn];

#pragma unroll
      for (int h = 0; h < 2; ++h) {        // k-halves: chunk q / q+4  (^32 elems)
        const int hx = h * 32;
        bf16x8 av[6], bv[4];
#pragma unroll
        for (int nf = 0; nf < 4; ++nf)
          bv[nf] = *(const bf16x8*)(Bs + soff + (baseB[nf] ^ hx));
#pragma unroll
        for (int f = 0; f < 6; ++f)
          av[f] = *(const bf16x8*)(As + (c0[f] ^ hx));
        __builtin_amdgcn_s_setprio(1);
#pragma unroll
        for (int mf = 0; mf < 6; ++mf)
#pragma unroll
          for (int nf = 0; nf < 4; ++nf)
            acc[mf][nf] = __builtin_amdgcn_mfma_f32_16x16x32_bf16(av[mf], bv[nf], acc[mf][nf], 0, 0, 0);
        __builtin_amdgcn_s_setprio(0);
      }

#pragma unroll
      for (int f = 0; f < 6; ++f) rowC[f] = rowN[f];

      __syncthreads();   // drains vmcnt: B(t+1) landed; all waves done with Bs[soff] (and As if r==23)

      // post slot: stage B(t+2) into the buffer just consumed; A at kb boundary
      if (r < 22) {
        stage_b(kb, r + 2, soff);
      } else if (kb < 7) {
        if (r == 22) {
          stage_b(kb + 1, 0, soff);
        } else {            // r == 23: safe to overwrite As now
          stage_a(kb + 1);
          stage_b(kb + 1, 1, soff);
          __syncthreads();  // extra drain (8x total) so next compute sees A(kb+1)
        }
      }
    }
  }

  // epilogue: D row = q*4+e (m), col = lm (n); add bias[o=col]
#pragma unroll
  for (int nf = 0; nf < 4; ++nf) {
    const int col = n0 + nw + nf * 16 + lm;
    const float bv = bias[col];
#pragma unroll
    for (int mf = 0; mf < 6; ++mf) {
      const int mrow = m0 + mw + mf * 16 + q * 4;
#pragma unroll
      for (int e = 0; e < 4; ++e)
        out[(size_t)(mrow + e) * N_DIM + col] = acc[mf][nf][e] + bv;
    }
  }
}

extern "C" void kernel_launch(void* const* d_in, const int* in_sizes, int n_in,
                              void* d_out, int out_size, void* d_ws, size_t ws_size,
                              hipStream_t stream) {
  (void)in_sizes; (void)n_in; (void)out_size; (void)ws_size;
  const float* x    = (const float*)d_in[0];
  const float* wgt  = (const float*)d_in[1];
  const float* bias = (const float*)d_in[2];
  const int*   po   = (const int*)d_in[3];
  float* out = (float*)d_out;

  u16* xb = (u16*)d_ws;                       // 25,165,824 elems = 50.3 MB
  u16* bt = xb + (size_t)M_DIM * CIN;         // 512*12288 elems = 12.6 MB

  const int nx4 = (BATCH * GSZ * CIN) / 4;
  convert_x<<<nx4 / 256, 256, 0, stream>>>(x, xb, nx4);
  build_bt<<<COUT, 256, 0, stream>>>(wgt, bt);

  const int grid = (M_DIM / BM) * (N_DIM / BN);  // 256*4 = 1024 (= 4 full CU rounds at 2 blocks/CU)
  gemm_gc<<<grid, 256, 0, stream>>>(xb, bt, bias, po, out);
}